// Round 6
// baseline (880.399 us; speedup 1.0000x reference)
//
#include <hip/hip_runtime.h>
#include <hip/hip_bf16.h>
#include <cstdint>
#include <cstddef>

typedef __bf16 bf16x8 __attribute__((ext_vector_type(8)));
typedef float f32x4 __attribute__((ext_vector_type(4)));
typedef float f32x16 __attribute__((ext_vector_type(16)));

#define MOD_SCALE 1.4731391e-02f   // 1/sqrt(512*9)
#define EPSF 1e-8f

// ---------------------------------------------------------------------------
// K1: s[b][i] = dot(style[b], mod_w[i]) + mod_b[i]
// ---------------------------------------------------------------------------
__global__ __launch_bounds__(512) void k_style(
    const float* __restrict__ style, const float* __restrict__ mod_w,
    const float* __restrict__ mod_b, float* __restrict__ s)
{
  __shared__ float st[512];
  const int b = blockIdx.x, i = threadIdx.x;
  st[i] = style[b*512 + i];
  __syncthreads();
  const float4* mw = (const float4*)(mod_w + (size_t)i*512);
  float acc = 0.f;
  #pragma unroll 8
  for (int j = 0; j < 128; ++j) {
    float4 v = mw[j];
    acc += v.x*st[4*j] + v.y*st[4*j+1] + v.z*st[4*j+2] + v.w*st[4*j+3];
  }
  s[b*512 + i] = acc + mod_b[i];
}

// ---------------------------------------------------------------------------
// K2: w2[o][i] = sum_kk weight^2 ; Wb[kk][o][i] = bf16(SCALE*weight)
// ---------------------------------------------------------------------------
__global__ __launch_bounds__(256) void k_weight(
    const float* __restrict__ weight, float* __restrict__ w2,
    __hip_bfloat16* __restrict__ Wb)
{
  const int o = blockIdx.x, t = threadIdx.x;
  #pragma unroll
  for (int h = 0; h < 2; ++h) {
    const int i = t + h*256;
    const float* wp = weight + ((size_t)o*512 + i)*9;
    float sq = 0.f;
    #pragma unroll
    for (int kk = 0; kk < 9; ++kk) {
      float v = wp[kk];
      sq += v*v;
      Wb[((size_t)kk*512 + o)*512 + i] = __float2bfloat16(v * MOD_SCALE);
    }
    w2[(size_t)o*512 + i] = sq;
  }
}

// ---------------------------------------------------------------------------
// K2b: demod[b][o] = rsqrt(SCALE^2 * sum_i s[b][i]^2 * w2[o][i] + eps)
// ---------------------------------------------------------------------------
__global__ __launch_bounds__(256) void k_demod(
    const float* __restrict__ s, const float* __restrict__ w2,
    float* __restrict__ demod)
{
  __shared__ float s2[512];
  const int b = blockIdx.x, t = threadIdx.x;
  {
    float a = s[b*512 + t];        s2[t]     = a*a;
    float c = s[b*512 + t + 256];  s2[t+256] = c*c;
  }
  __syncthreads();
  #pragma unroll
  for (int h = 0; h < 2; ++h) {
    const int o = t + h*256;
    const float4* wp = (const float4*)(w2 + (size_t)o*512);
    float acc = 0.f;
    #pragma unroll 8
    for (int j = 0; j < 128; ++j) {
      float4 v = wp[j];
      acc += v.x*s2[4*j] + v.y*s2[4*j+1] + v.z*s2[4*j+2] + v.w*s2[4*j+3];
    }
    demod[b*512 + o] = rsqrtf(MOD_SCALE*MOD_SCALE*acc + EPSF);
  }
}

// ---------------------------------------------------------------------------
// K3: Xm[b][py][px][i] = bf16(s[b][i] * x[b][i][py-1][px-1]); writes own halo.
// ---------------------------------------------------------------------------
__global__ __launch_bounds__(256) void k_xm(
    const float* __restrict__ x, const float* __restrict__ s,
    __hip_bfloat16* __restrict__ Xm)
{
  __shared__ __hip_bfloat16 T[64][40];
  const int bid = blockIdx.x;
  const int cb = bid & 15, y = (bid >> 4) & 63, b = bid >> 10;
  const int ic0 = cb*32;
  const int t = threadIdx.x;
  const int i = t >> 3, x0 = (t & 7)*8;
  const float sv = s[b*512 + ic0 + i];
  const float4* xp = (const float4*)(x + (size_t)(b*512 + ic0 + i)*4096 + y*64 + x0);
  float4 v0 = xp[0], v1 = xp[1];
  float vals[8] = {v0.x, v0.y, v0.z, v0.w, v1.x, v1.y, v1.z, v1.w};
  #pragma unroll
  for (int j = 0; j < 8; ++j) T[x0+j][i] = __float2bfloat16(vals[j]*sv);

  const float4 z4 = make_float4(0.f, 0.f, 0.f, 0.f);
  if (t < 8) {
    const int side = t >> 2, j = t & 3;
    float4* hz = (float4*)(Xm + (((size_t)(b*66 + (y+1))*66 + side*65)*512 + ic0 + j*8));
    *hz = z4;
  }
  if (y == 0) {
    for (int idx = t; idx < 264; idx += 256) {
      const int px = idx >> 2, j = idx & 3;
      float4* hz = (float4*)(Xm + (((size_t)(b*66 + 0)*66 + px)*512 + ic0 + j*8));
      *hz = z4;
    }
  }
  if (y == 63) {
    for (int idx = t; idx < 264; idx += 256) {
      const int px = idx >> 2, j = idx & 3;
      float4* hz = (float4*)(Xm + (((size_t)(b*66 + 65)*512*66/512 + px)*512 + ic0 + j*8));
      *hz = z4;
    }
  }

  __syncthreads();
  const int p = t >> 2, c = (t & 3)*8;
  __hip_bfloat16* dst = Xm + (((size_t)(b*66 + (y+1))*66 + (p+1))*512 + ic0 + c);
  *(float4*)dst = *(const float4*)&T[p][c];
}

// ---------------------------------------------------------------------------
// K4: conv as implicit GEMM, NO LDS — direct L2->register MFMA pipeline.
// Block: 256 thr = 4 waves (2M x 2N), wave tile 128x64 (4x2 frags of 32x32),
// block tile 256 M x 128 N.  Grid 1024 = 16 b x 2 mt x 32 nt, XCD-swizzled.
// K = 144 sub-tiles of BK=32 (9 taps x 16 ch-chunks); per sub-tile per wave:
// 12 global_load_dwordx4 (saddr+voff+imm) + 16 mfma_32x32x16_bf16.
// Register double-buffer (sets A/B) pipelines loads of t+1 under MFMA of t.
// No barriers, no staging, no vmcnt choreography — waves free-run.
// ---------------------------------------------------------------------------
__global__ __launch_bounds__(256) void k_conv(
    const __hip_bfloat16* __restrict__ Wb,   // [9][512][512]
    const __hip_bfloat16* __restrict__ Xm,   // [16][66][66][512]
    const float* __restrict__ demod,         // [16][512]
    float* __restrict__ out)                 // [16][512][64][64]
{
  const int orig = blockIdx.x;
  const int swz = (orig & 7)*128 + (orig >> 3);   // bijective (1024 % 8 == 0)
  const int b  = swz >> 6;
  const int mt = (swz >> 5) & 1;
  const int nt = swz & 31;

  const int tid = threadIdx.x;
  const int l = tid & 63;
  const int w = tid >> 6;
  const int wmb = w >> 1, wnb = w & 1;

  const char* WbC = (const char*)Wb;
  const char* XmC = (const char*)Xm + (size_t)b*4356*1024;   // Xm[b]

  // per-lane 32-bit byte offsets (uniform base goes to SGPR -> saddr form)
  int v_offA[4], v_offB[2];
  #pragma unroll
  for (int am = 0; am < 4; ++am)
    v_offA[am] = (mt*256 + wmb*128 + am*32 + (l & 31))*1024 + ((l >> 5) << 4);
  #pragma unroll
  for (int ni = 0; ni < 2; ++ni) {
    const int ncl = wnb*64 + ni*32 + (l & 31);
    v_offB[ni] = ((ncl >> 6)*66 + (ncl & 63))*1024 + ((l >> 5) << 4);
  }

  f32x16 acc[4][2] = {};
  bf16x8 aA[4][2], bA[2][2], aB[4][2], bB[2][2];

  // sub-tile t: kk = t>>4 (tap), ch-chunk = (t&15)*32 channels
  #define LOADS(t, Adst, Bdst) do { \
    const int kk_ = (t) >> 4; \
    const int icb_ = ((t) & 15) << 6; \
    const int dy_ = kk_/3 - 1, dx_ = kk_ - (kk_/3)*3 - 1; \
    const char* pa_ = WbC + kk_*524288 + icb_; \
    const char* pb_ = XmC + (size_t)((nt*2 + 1 + dy_)*66 + 1 + dx_)*1024 + icb_; \
    _Pragma("unroll") \
    for (int am_ = 0; am_ < 4; ++am_) \
      _Pragma("unroll") \
      for (int ks_ = 0; ks_ < 2; ++ks_) \
        Adst[am_][ks_] = *(const bf16x8*)(pa_ + v_offA[am_] + ks_*32); \
    _Pragma("unroll") \
    for (int ni_ = 0; ni_ < 2; ++ni_) \
      _Pragma("unroll") \
      for (int ks_ = 0; ks_ < 2; ++ks_) \
        Bdst[ni_][ks_] = *(const bf16x8*)(pb_ + v_offB[ni_] + ks_*32); \
  } while(0)

  #define MM(Asrc, Bsrc) do { \
    _Pragma("unroll") \
    for (int ks_ = 0; ks_ < 2; ++ks_) \
      _Pragma("unroll") \
      for (int am_ = 0; am_ < 4; ++am_) \
        _Pragma("unroll") \
        for (int ni_ = 0; ni_ < 2; ++ni_) \
          acc[am_][ni_] = __builtin_amdgcn_mfma_f32_32x32x16_bf16( \
              Asrc[am_][ks_], Bsrc[ni_][ks_], acc[am_][ni_], 0, 0, 0); \
  } while(0)

  LOADS(0, aA, bA);
  #pragma unroll 1
  for (int t = 0; t < 142; t += 2) {
    LOADS(t+1, aB, bB);
    MM(aA, bA);
    LOADS(t+2, aA, bA);
    MM(aB, bB);
  }
  LOADS(143, aB, bB);
  MM(aA, bA);
  MM(aB, bB);

  // epilogue: demod scale, NCHW fp32 store.
  // C/D 32x32 layout: col=l&31 (N), row=(r&3)+8*(r>>2)+4*(l>>5), r=g*4+j.
  const int lr = l & 31;
  #pragma unroll
  for (int am = 0; am < 4; ++am) {
    const int om = mt*256 + wmb*128 + am*32 + ((l >> 5) << 2);
    #pragma unroll
    for (int ni = 0; ni < 2; ++ni) {
      const int ncl = wnb*64 + ni*32 + lr;
      const int y = nt*2 + (ncl >> 6), xx = ncl & 63;
      #pragma unroll
      for (int g = 0; g < 4; ++g) {
        const f32x4 dm = *(const f32x4*)(demod + b*512 + om + 8*g);
        float* op = out + (size_t)(b*512 + om + 8*g)*4096 + y*64 + xx;
        #pragma unroll
        for (int j = 0; j < 4; ++j)
          op[(size_t)j*4096] = acc[am][ni][g*4 + j] * dm[j];
      }
    }
  }
  #undef LOADS
  #undef MM
}

// ---------------------------------------------------------------------------
extern "C" void kernel_launch(void* const* d_in, const int* in_sizes, int n_in,
                              void* d_out, int out_size, void* d_ws, size_t ws_size,
                              hipStream_t stream)
{
  const float* x      = (const float*)d_in[0];
  const float* style  = (const float*)d_in[1];
  const float* weight = (const float*)d_in[2];
  const float* mod_w  = (const float*)d_in[3];
  const float* mod_b  = (const float*)d_in[4];
  float* out = (float*)d_out;

  char* ws = (char*)d_ws;
  float* s            = (float*)(ws);                  //  32 KB  [16][512]
  float* demod        = (float*)(ws + 32768);          //  32 KB  [16][512]
  float* w2           = (float*)(ws + 65536);          //   1 MB  [512][512]
  __hip_bfloat16* Wb  = (__hip_bfloat16*)(ws + 1114112);   // 4.5 MB [9][512][512]
  __hip_bfloat16* Xm  = (__hip_bfloat16*)(ws + 5832704);   // 71.4 MB [16][66][66][512]

  k_style <<<16,    512, 0, stream>>>(style, mod_w, mod_b, s);
  k_weight<<<512,   256, 0, stream>>>(weight, w2, Wb);
  k_demod <<<16,    256, 0, stream>>>(s, w2, demod);
  k_xm    <<<16384, 256, 0, stream>>>(x, s, Xm);
  k_conv  <<<1024,  256, 0, stream>>>(Wb, Xm, demod, out);
}

// Round 7
// 391.848 us; speedup vs baseline: 2.2468x; 2.2468x over previous
//
#include <hip/hip_runtime.h>
#include <hip/hip_bf16.h>
#include <cstdint>
#include <cstddef>

typedef __bf16 bf16x8 __attribute__((ext_vector_type(8)));
typedef float f32x4 __attribute__((ext_vector_type(4)));
typedef float f32x16 __attribute__((ext_vector_type(16)));

#define MOD_SCALE 1.4731391e-02f   // 1/sqrt(512*9)
#define EPSF 1e-8f

// ---------------------------------------------------------------------------
// K1: s[b][i] = dot(style[b], mod_w[i]) + mod_b[i]
// ---------------------------------------------------------------------------
__global__ __launch_bounds__(512) void k_style(
    const float* __restrict__ style, const float* __restrict__ mod_w,
    const float* __restrict__ mod_b, float* __restrict__ s)
{
  __shared__ float st[512];
  const int b = blockIdx.x, i = threadIdx.x;
  st[i] = style[b*512 + i];
  __syncthreads();
  const float4* mw = (const float4*)(mod_w + (size_t)i*512);
  float acc = 0.f;
  #pragma unroll 8
  for (int j = 0; j < 128; ++j) {
    float4 v = mw[j];
    acc += v.x*st[4*j] + v.y*st[4*j+1] + v.z*st[4*j+2] + v.w*st[4*j+3];
  }
  s[b*512 + i] = acc + mod_b[i];
}

// ---------------------------------------------------------------------------
// K2: w2[o][i] = sum_kk weight^2 ; Wb[kk][o][i] = bf16(SCALE*weight)
// ---------------------------------------------------------------------------
__global__ __launch_bounds__(256) void k_weight(
    const float* __restrict__ weight, float* __restrict__ w2,
    __hip_bfloat16* __restrict__ Wb)
{
  const int o = blockIdx.x, t = threadIdx.x;
  #pragma unroll
  for (int h = 0; h < 2; ++h) {
    const int i = t + h*256;
    const float* wp = weight + ((size_t)o*512 + i)*9;
    float sq = 0.f;
    #pragma unroll
    for (int kk = 0; kk < 9; ++kk) {
      float v = wp[kk];
      sq += v*v;
      Wb[((size_t)kk*512 + o)*512 + i] = __float2bfloat16(v * MOD_SCALE);
    }
    w2[(size_t)o*512 + i] = sq;
  }
}

// ---------------------------------------------------------------------------
// K2b: demod[b][o] = rsqrt(SCALE^2 * sum_i s[b][i]^2 * w2[o][i] + eps)
// ---------------------------------------------------------------------------
__global__ __launch_bounds__(256) void k_demod(
    const float* __restrict__ s, const float* __restrict__ w2,
    float* __restrict__ demod)
{
  __shared__ float s2[512];
  const int b = blockIdx.x, t = threadIdx.x;
  {
    float a = s[b*512 + t];        s2[t]     = a*a;
    float c = s[b*512 + t + 256];  s2[t+256] = c*c;
  }
  __syncthreads();
  #pragma unroll
  for (int h = 0; h < 2; ++h) {
    const int o = t + h*256;
    const float4* wp = (const float4*)(w2 + (size_t)o*512);
    float acc = 0.f;
    #pragma unroll 8
    for (int j = 0; j < 128; ++j) {
      float4 v = wp[j];
      acc += v.x*s2[4*j] + v.y*s2[4*j+1] + v.z*s2[4*j+2] + v.w*s2[4*j+3];
    }
    demod[b*512 + o] = rsqrtf(MOD_SCALE*MOD_SCALE*acc + EPSF);
  }
}

// ---------------------------------------------------------------------------
// K3: Xm[b][py][px][i] = bf16(s[b][i] * x[b][i][py-1][px-1]); writes own halo.
// ---------------------------------------------------------------------------
__global__ __launch_bounds__(256) void k_xm(
    const float* __restrict__ x, const float* __restrict__ s,
    __hip_bfloat16* __restrict__ Xm)
{
  __shared__ __hip_bfloat16 T[64][40];
  const int bid = blockIdx.x;
  const int cb = bid & 15, y = (bid >> 4) & 63, b = bid >> 10;
  const int ic0 = cb*32;
  const int t = threadIdx.x;
  const int i = t >> 3, x0 = (t & 7)*8;
  const float sv = s[b*512 + ic0 + i];
  const float4* xp = (const float4*)(x + (size_t)(b*512 + ic0 + i)*4096 + y*64 + x0);
  float4 v0 = xp[0], v1 = xp[1];
  float vals[8] = {v0.x, v0.y, v0.z, v0.w, v1.x, v1.y, v1.z, v1.w};
  #pragma unroll
  for (int j = 0; j < 8; ++j) T[x0+j][i] = __float2bfloat16(vals[j]*sv);

  const float4 z4 = make_float4(0.f, 0.f, 0.f, 0.f);
  if (t < 8) {
    const int side = t >> 2, j = t & 3;
    float4* hz = (float4*)(Xm + (((size_t)(b*66 + (y+1))*66 + side*65)*512 + ic0 + j*8));
    *hz = z4;
  }
  if (y == 0) {
    for (int idx = t; idx < 264; idx += 256) {
      const int px = idx >> 2, j = idx & 3;
      float4* hz = (float4*)(Xm + (((size_t)(b*66 + 0)*66 + px)*512 + ic0 + j*8));
      *hz = z4;
    }
  }
  if (y == 63) {
    for (int idx = t; idx < 264; idx += 256) {
      const int px = idx >> 2, j = idx & 3;
      float4* hz = (float4*)(Xm + (((size_t)(b*66 + 65)*66 + px)*512 + ic0 + j*8));
      *hz = z4;
    }
  }

  __syncthreads();
  const int p = t >> 2, c = (t & 3)*8;
  __hip_bfloat16* dst = Xm + (((size_t)(b*66 + (y+1))*66 + (p+1))*512 + ic0 + c);
  *(float4*)dst = *(const float4*)&T[p][c];
}

// ---------------------------------------------------------------------------
// K4: conv as implicit GEMM, 256x256 tile, 32x32x16 MFMA, R5's proven
// Phi+XOR LDS layout (0 conflicts) — now with ONE barrier + ONE vmcnt(0)
// per K-tile.  All stages target the non-read buffer, so phases within a
// tile have no LDS hazards; reads/MFMA free-run in 4 balanced ks-phases
// (6 ds_read_b128 + 8 MFMA each) and overlap across the 2 waves/SIMD.
// Stage loads are issued at tile top => ~full tile in flight => vmcnt(0)
// at tile end is nearly free (unlike the m97 per-step drain).
// ---------------------------------------------------------------------------
#define VMC(n) asm volatile("s_waitcnt vmcnt(" #n ")" ::: "memory")

__global__ __launch_bounds__(512, 2) void k_conv(
    const __hip_bfloat16* __restrict__ Wb,   // [9][512][512]
    const __hip_bfloat16* __restrict__ Xm,   // [16][66][66][512]
    const float* __restrict__ demod,         // [16][512]
    float* __restrict__ out)                 // [16][512][64][64]
{
  __shared__ __hip_bfloat16 lds[2][2][16384];   // [buf][A=0/B=1][256*64]

  const int orig = blockIdx.x;
  const int swz = (orig & 7)*64 + (orig >> 3);   // bijective XCD swizzle (512%8==0)
  const int b  = swz >> 5;
  const int nt = (swz & 31) >> 1;
  const int mt = swz & 1;
  const int o0 = mt*256, y0 = nt*4;

  const int tid = threadIdx.x;
  const int l = tid & 63;
  const int w = tid >> 6;
  const int wm = w >> 2;       // 0..1
  const int wn = w & 3;        // 0..3

  // ---- staging constants: linear LDS dest; Phi+swz folded into source ----
  const int srow = tid >> 3;                      // 0..63 (physical row mod 64)
  const int tq   = (tid & 7) ^ (srow & 7);        // t = q ^ (R&7)
  const char* WbC = (const char*)Wb;
  const char* XmC = (const char*)Xm;

  // ---- frag-read constants (32x32 frag: row=l&31, k-half=(l>>5)) ----
  const int rowb = ((l >> 5) << 4) | (l & 15);    // physical row in 32-group
  const int lb4  = (l >> 4) & 1;
  const int sB   = (l & 7) << 4;

  #define STAGE_A(tau, h, bfi) do { \
    const int kk_ = (tau) >> 3; \
    const int cb_ = ((tau) & 7) << 7; \
    _Pragma("unroll") \
    for (int it_ = 0; it_ < 2; ++it_) { \
      const int R_ = it_*64 + srow; \
      const int gr_ = (R_ & 0x6F) | ((tq & 1) << 4); \
      const int gc_ = ((tq & 6) | ((R_ >> 4) & 1)) << 4; \
      const char* src_ = WbC + (size_t)(kk_*512 + o0 + (h)*128 + gr_)*1024 + cb_ + gc_; \
      __builtin_amdgcn_global_load_lds( \
        (__attribute__((address_space(1))) void*)src_, \
        (__attribute__((address_space(3))) void*)((char*)&lds[bfi][0][0] + (h)*16384 + it_*8192 + w*1024), \
        16, 0, 0); \
    } \
  } while(0)

  #define STAGE_B(tau, h, bfi) do { \
    const int kk_ = (tau) >> 3; \
    const int cb_ = ((tau) & 7) << 7; \
    const int dy_ = kk_/3 - 1, dx_ = kk_ - (kk_/3)*3 - 1; \
    _Pragma("unroll") \
    for (int it_ = 0; it_ < 2; ++it_) { \
      const int R_ = it_*64 + srow; \
      const int gr_ = (R_ & 0x6F) | ((tq & 1) << 4); \
      const int gc_ = ((tq & 6) | ((R_ >> 4) & 1)) << 4; \
      const int py_ = y0 + (h)*2 + (gr_ >> 6) + dy_ + 1; \
      const int px_ = (gr_ & 63) + dx_ + 1; \
      const char* src_ = XmC + ((size_t)((b*66 + py_)*66 + px_))*1024 + cb_ + gc_; \
      __builtin_amdgcn_global_load_lds( \
        (__attribute__((address_space(1))) void*)src_, \
        (__attribute__((address_space(3))) void*)((char*)&lds[bfi][1][0] + (h)*16384 + it_*8192 + w*1024), \
        16, 0, 0); \
    } \
  } while(0)

  #define STAGE_TILE(tau, bfi) do { \
    STAGE_A(tau, 0, bfi); STAGE_A(tau, 1, bfi); \
    STAGE_B(tau, 0, bfi); STAGE_B(tau, 1, bfi); \
  } while(0)

  f32x16 acc[4][2] = {};

  // One K-tile: issue next tile's 8 glds, then 4 balanced ks-phases of
  // {4 A-reads + 2 B-reads + 8 MFMA}; vmcnt(0) + barrier at tile end.
  #define TILE(BFI, STG, VMCW, BAR) do { \
    const char* Ab_ = (const char*)&lds[BFI][0][0]; \
    const char* Bb_ = (const char*)&lds[BFI][1][0]; \
    STG; \
    _Pragma("unroll") \
    for (int p_ = 0; p_ < 4; ++p_) { \
      bf16x8 a_[4], b_[2]; \
      const int kc_ = (((p_ << 1) | lb4) << 4) ^ sB; \
      _Pragma("unroll") \
      for (int j_ = 0; j_ < 4; ++j_) \
        a_[j_] = *(const bf16x8*)(Ab_ + (j_ >> 1)*16384 + wm*8192 + (j_ & 1)*4096 \
                                  + rowb*128 + kc_); \
      _Pragma("unroll") \
      for (int nh_ = 0; nh_ < 2; ++nh_) \
        b_[nh_] = *(const bf16x8*)(Bb_ + nh_*16384 + wn*4096 + rowb*128 + kc_); \
      __builtin_amdgcn_s_setprio(1); \
      _Pragma("unroll") \
      for (int j_ = 0; j_ < 4; ++j_) \
        _Pragma("unroll") \
        for (int nh_ = 0; nh_ < 2; ++nh_) \
          acc[j_][nh_] = __builtin_amdgcn_mfma_f32_32x32x16_bf16( \
              a_[j_], b_[nh_], acc[j_][nh_], 0, 0, 0); \
      __builtin_amdgcn_s_setprio(0); \
    } \
    VMCW; \
    if (BAR) __builtin_amdgcn_s_barrier(); \
  } while(0)

  // prologue: tile 0 into buf 0
  STAGE_TILE(0, 0);
  VMC(0);
  __builtin_amdgcn_s_barrier();

  #pragma unroll 1
  for (int tt = 0; tt < 35; ++tt) {
    const int t = tt*2;
    TILE(0, STAGE_TILE(t+1, 1), VMC(0), 1);
    TILE(1, STAGE_TILE(t+2, 0), VMC(0), 1);
  }
  TILE(0, STAGE_TILE(71, 1), VMC(0), 1);
  TILE(1, (void)0, (void)0, 0);

  // epilogue: demod scale, NCHW fp32 store.
  // C/D 32x32 layout: col=l&31 (N), row=(r&3)+8*(r>>2)+4*(l>>5), r=g*4+j.
  const int lr = l & 31;
  #pragma unroll
  for (int am = 0; am < 4; ++am) {
    const int om = o0 + (am >> 1)*128 + wm*64 + (am & 1)*32 + ((l >> 5) << 2);
    #pragma unroll
    for (int NH = 0; NH < 2; ++NH) {
      const int nc = NH*128 + wn*32 + lr;
      const int y = y0 + (nc >> 6), xx = nc & 63;
      #pragma unroll
      for (int g = 0; g < 4; ++g) {
        const f32x4 dm = *(const f32x4*)(demod + b*512 + om + 8*g);
        float* op = out + (size_t)(b*512 + om + 8*g)*4096 + y*64 + xx;
        #pragma unroll
        for (int j = 0; j < 4; ++j)
          op[(size_t)j*4096] = acc[am][NH][g*4 + j] * dm[j];
      }
    }
  }
  #undef TILE
  #undef STAGE_TILE
  #undef STAGE_A
  #undef STAGE_B
}

// ---------------------------------------------------------------------------
extern "C" void kernel_launch(void* const* d_in, const int* in_sizes, int n_in,
                              void* d_out, int out_size, void* d_ws, size_t ws_size,
                              hipStream_t stream)
{
  const float* x      = (const float*)d_in[0];
  const float* style  = (const float*)d_in[1];
  const float* weight = (const float*)d_in[2];
  const float* mod_w  = (const float*)d_in[3];
  const float* mod_b  = (const float*)d_in[4];
  float* out = (float*)d_out;

  char* ws = (char*)d_ws;
  float* s            = (float*)(ws);                  //  32 KB  [16][512]
  float* demod        = (float*)(ws + 32768);          //  32 KB  [16][512]
  float* w2           = (float*)(ws + 65536);          //   1 MB  [512][512]
  __hip_bfloat16* Wb  = (__hip_bfloat16*)(ws + 1114112);   // 4.5 MB [9][512][512]
  __hip_bfloat16* Xm  = (__hip_bfloat16*)(ws + 5832704);   // 71.4 MB [16][66][66][512]

  k_style <<<16,    512, 0, stream>>>(style, mod_w, mod_b, s);
  k_weight<<<512,   256, 0, stream>>>(weight, w2, Wb);
  k_demod <<<16,    256, 0, stream>>>(s, w2, demod);
  k_xm    <<<16384, 256, 0, stream>>>(x, s, Xm);
  k_conv  <<<512,   512, 0, stream>>>(Wb, Xm, demod, out);
}